// Round 9
// baseline (252.097 us; speedup 1.0000x reference)
//
#include <hip/hip_runtime.h>

#define BB 4
#define CC 256
#define HH 96
#define WW 128
#define PP 9
#define OFF 4
#define CCH 16           // channels per chunk
#define NPAIR (CCH / 2)  // 8 f16x2 channel pairs per chunk
#define NCH (CC / CCH)   // 16 chunks
#define TPB 288          // 9 dy * 32 pixel-groups
#define TW 72            // staged in2 cols (64 out + 8 halo)
#define XCOLS 64         // output columns per block

typedef _Float16 h2 __attribute__((ext_vector_type(2)));

__device__ __forceinline__ h2 u2h(unsigned u) { union { unsigned u; h2 h; } x; x.u = u; return x.h; }

#if __has_builtin(__builtin_amdgcn_fdot2)
__device__ __forceinline__ float dot2(h2 a, h2 b, float c) { return __builtin_amdgcn_fdot2(a, b, c, false); }
#else
__device__ __forceinline__ float dot2(h2 a, h2 b, float c) { return c + (float)a[0] * (float)b[0] + (float)a[1] * (float)b[1]; }
#endif

__device__ __forceinline__ unsigned pk(float a, float b) {
#if __has_builtin(__builtin_amdgcn_cvt_pkrtz)
  auto r = __builtin_amdgcn_cvt_pkrtz(a, b);
  unsigned u; __builtin_memcpy(&u, &r, 4); return u;
#else
  h2 h; h[0] = (_Float16)a; h[1] = (_Float16)b;
  unsigned u; __builtin_memcpy(&u, &h, 4); return u;
#endif
}

// 768 blocks (4b*96h*2xh, = exactly 3/CU) x 288 thr. SINGLE 22.8 KB LDS
// buffer (R5's, best so far) but R7's loop order so the global prefetch is
// intra-iteration live (not sunk): load(c+1) -> compute(c) -> barrier ->
// store(c+1) -> barrier. launch_bounds(288,3): VGPR cap ~170, no spill.
__global__ __launch_bounds__(TPB, 3) void corr_kernel(const float* __restrict__ in1,
                                                      const float* __restrict__ in2,
                                                      float* __restrict__ out) {
  __shared__ unsigned s2[NPAIR][PP][TW];   // 20736 B
  __shared__ unsigned s1[NPAIR][XCOLS];    // 2048 B -> 22.8 KB total

  // XCD swizzle: 12-row h-band per XCD so the 9-row dy-halo stays in-XCD L2.
  const int bx = blockIdx.x;
  const int xcd = bx & 7;
  const int slot = bx >> 3;            // 0..95
  const int xh = slot & 1;
  const int s3 = slot >> 1;            // 0..47
  const int b = s3 / 12;
  const int h = xcd * 12 + (s3 % 12);
  const int xbase = xh * XCOLS;

  const int tid = threadIdx.x;
  const int dy = tid >> 5;             // 0..8
  const int pxg = tid & 31;            // 0..31
  const int L0 = pxg << 1;             // 2 output px -> lds cols L0, L0+1

  // staging role: 288 = 8 pairs * 36 col-pairs; edge pairs fully OOB.
  const int sp = tid / 36;             // channel pair 0..7
  const int sc2 = tid - sp * 36;       // col-pair 0..35
  const int sL = sc2 << 1;
  const int sgx = xbase - OFF + sL;    // global x of staged pair (even)
  const bool colv = (sgx >= 0) && (sgx < WW);
  const int sgxc = colv ? sgx : xbase; // clamped: loads always in-bounds
  const int rlo = (h >= OFF) ? 0 : (OFF - h);          // block-uniform
  const int rhi = (PP < HH + OFF - h) ? PP : (HH + OFF - h);

  const int plane = HH * WW;           // 12288
  const long base_b = (long)b * CC * plane;

  // clamped row offsets (block-uniform); loads are fully branch-free
  int rowoff[PP];
#pragma unroll
  for (int r = 0; r < PP; ++r) {
    int hr = h + r - OFF;
    hr = hr < 0 ? 0 : (hr >= HH ? HH - 1 : hr);
    rowoff[r] = hr * WW;
  }

  const float* p2a = in2 + base_b + (long)(2 * sp) * plane + sgxc;
  const float* p2b = p2a + plane;
  const int i1p = (tid >> 5) & 7, i1c = tid & 31;
  const bool in1v = (tid < NPAIR * 32);
  const float* p1a = in1 + base_b + (long)(2 * i1p) * plane + h * WW + xbase + (i1c << 1);
  const float* p1b = p1a + plane;

  // pre-zero s2 once: OOB rows/cols never overwritten afterwards
  for (int i = tid; i < NPAIR * PP * TW; i += TPB) ((unsigned*)s2)[i] = 0u;

  float acc[2][PP];
#pragma unroll
  for (int px = 0; px < 2; ++px)
#pragma unroll
    for (int dx = 0; dx < PP; ++dx) acc[px][dx] = 0.f;

  float2 fa[PP], fb[PP], ga, gb;

  // ---- chunk 0: load (branch-free), store to LDS
#pragma unroll
  for (int r = 0; r < PP; ++r) {
    fa[r] = *(const float2*)(p2a + rowoff[r]);
    fb[r] = *(const float2*)(p2b + rowoff[r]);
  }
  ga = *(const float2*)p1a; gb = *(const float2*)p1b;
  __syncthreads();  // pre-zero visible
  if (colv) {
#pragma unroll
    for (int r = 0; r < PP; ++r)
      if (r >= rlo && r < rhi)
        *(uint2*)&s2[sp][r][sL] = make_uint2(pk(fa[r].x, fb[r].x), pk(fa[r].y, fb[r].y));
  }
  if (in1v)
    *(uint2*)&s1[i1p][i1c << 1] = make_uint2(pk(ga.x, gb.x), pk(ga.y, gb.y));
  __syncthreads();  // chunk 0 visible

#pragma unroll 1
  for (int c = 0; c < NCH; ++c) {
    // ---- load chunk c+1 into regs (branch-free; consumed after compute,
    // so the vmcnt drain is hidden behind ~500 cyc of dot2 work)
    if (c + 1 < NCH) {
      const long adv = (long)(c + 1) * CCH * plane;
#pragma unroll
      for (int r = 0; r < PP; ++r) {
        fa[r] = *(const float2*)(p2a + adv + rowoff[r]);
        fb[r] = *(const float2*)(p2b + adv + rowoff[r]);
      }
      ga = *(const float2*)(p1a + adv); gb = *(const float2*)(p1b + adv);
    }

    // ---- compute chunk c: 2px x 9dx sliding f16x2 window
#pragma unroll
    for (int p = 0; p < NPAIR; ++p) {
      unsigned q[2], w[10];
      *(uint2*)q = *(const uint2*)&s1[p][L0];
#pragma unroll
      for (int i = 0; i < 5; ++i)
        *(uint2*)&w[2 * i] = *(const uint2*)&s2[p][dy][L0 + 2 * i];
#pragma unroll
      for (int px = 0; px < 2; ++px)
#pragma unroll
        for (int dx = 0; dx < PP; ++dx)
          acc[px][dx] = dot2(u2h(w[px + dx]), u2h(q[px]), acc[px][dx]);
    }
    __syncthreads();  // A: all compute reads of the single buffer done

    // ---- store chunk c+1 into the same buffer
    if (c + 1 < NCH) {
      if (colv) {
#pragma unroll
        for (int r = 0; r < PP; ++r)
          if (r >= rlo && r < rhi)
            *(uint2*)&s2[sp][r][sL] = make_uint2(pk(fa[r].x, fb[r].x), pk(fa[r].y, fb[r].y));
      }
      if (in1v)
        *(uint2*)&s1[i1p][i1c << 1] = make_uint2(pk(ga.x, gb.x), pk(ga.y, gb.y));
    }
    __syncthreads();  // B: chunk c+1 visible
  }

  // ---- epilogue: 9 coalesced float2 stores
  const int gx0 = xbase + L0;
  float* ob = out + ((long)(b * PP + dy) * PP) * plane + h * WW + gx0;
#pragma unroll
  for (int dx = 0; dx < PP; ++dx)
    *(float2*)(ob + (long)dx * plane) = make_float2(acc[0][dx], acc[1][dx]);
}

extern "C" void kernel_launch(void* const* d_in, const int* in_sizes, int n_in,
                              void* d_out, int out_size, void* d_ws, size_t ws_size,
                              hipStream_t stream) {
  const float* in1 = (const float*)d_in[0];
  const float* in2 = (const float*)d_in[1];
  float* out = (float*)d_out;
  // 768 blocks = 4b * 96h * 2xh (xcd-swizzled), 288 thr = 9dy * 32pxg
  corr_kernel<<<dim3(BB * HH * 2), dim3(TPB), 0, stream>>>(in1, in2, out);
}